// Round 7
// baseline (1304.366 us; speedup 1.0000x reference)
//
#include <hip/hip_runtime.h>
#include <stdint.h>

#define KOFF 27
#define CIN 64
#define COUT 128
#define EPS 1e-5f

using frag_ab = __attribute__((ext_vector_type(8))) short;
using frag_cd = __attribute__((ext_vector_type(4))) float;

__device__ __forceinline__ float bf2f(unsigned short u) {
  union { unsigned int i; float f; } x; x.i = ((unsigned int)u) << 16; return x.f;
}
__device__ __forceinline__ unsigned short f2bf(float f) {
  union { float f; unsigned int i; } x; x.f = f;
  unsigned int u = x.i;
  u += 0x7fffu + ((u >> 16) & 1u);   // round-to-nearest-even
  return (unsigned short)(u >> 16);
}

// ---------------------------------------------------------------------------
// Gather-GEMM (round 7): Y[row] = sum_k X[nbr[k][row]] @ W[k].
// R5 skeleton (K=64 steps, __syncthreads, 2-buffer LDS ping-pong, same
// 8-sector XOR swizzle, B JIT in registers) with ONE change: A staging is
// REG-STAGED (T14) instead of global_load_lds.
//   iter t: barrier; ds_write set(t+1)->buf[(t+1)&1]; issue global loads
//           set(t+2) into named reg set; loadB(t); mfma(buf[t&1]).
// Loads get a full iteration of latency cover; VMEM returns land in
// registers (no direct-to-LDS return-path serialization); ds_writes are 4
// conflict-free b128/wave/step. LDS layout/read side identical to R5.
// idx queue: at issue of step u, idxc = idx(ko(u)); advanced on ko change.
// Fused BN stats via zero-page trick + atomics.
// ---------------------------------------------------------------------------
template <int CI, bool GATHER, bool OF32>
__global__ __launch_bounds__(256, 3) void conv_kernel(
    const unsigned short* __restrict__ X, const int* __restrict__ nbr,
    const unsigned short* __restrict__ Wt, void* __restrict__ Yv,
    const unsigned short* __restrict__ zpage, float* __restrict__ sums,
    int n, int koff) {
  constexpr int SUB = CI / 64;  // 64-ch sub-chunks per offset (1 or 2)
  __shared__ unsigned short Alds[2][128 * 64];  // 2 x 16 KB ping-pong

  const int tid = threadIdx.x;
  const int lane = tid & 63;
  const int wave = tid >> 6;
  const int row0 = blockIdx.x * 128;
  const int wrow = (wave >> 1) * 64;
  const int wcol = (wave & 1) * 64;
  const int m = lane & 15;
  const int q = lane >> 4;
  const int g8 = ((lane & 7) ^ (lane >> 3)) * 8;  // swizzled sector (ushorts)

  frag_cd acc[4][4];
#pragma unroll
  for (int i = 0; i < 4; ++i)
#pragma unroll
    for (int j = 0; j < 4; ++j) acc[i][j] = (frag_cd){0.f, 0.f, 0.f, 0.f};

  frag_ab b[2][4];
  uint4 P0[4], P1[4];  // pending A sets (even/odd steps) — static indexing
  int idxc[4];

  auto load_idx = [&](int ko, int (&dst)[4]) {
#pragma unroll
    for (int c = 0; c < 4; ++c) {
      const int grow = row0 + wave * 32 + c * 8 + (lane >> 3);
      int v = -1;
      if (grow < n) v = GATHER ? nbr[(size_t)ko * n + grow] : grow;
      dst[c] = v;
    }
  };
  // issue 4 x 16 B gathered loads for step u into reg set P
  auto issueA = [&](uint4 (&P)[4], int u, const int (&idx)[4]) {
    const int ch = (SUB == 2 ? (u & 1) * 64 : 0) + g8;
#pragma unroll
    for (int c = 0; c < 4; ++c) {
      const unsigned short* ga =
          (idx[c] >= 0) ? X + (size_t)idx[c] * CI + ch : zpage;
      P[c] = *(const uint4*)ga;
    }
  };
  // ds_write reg set into buf; layout identical to what gld16 produced in R5:
  // instr c covers rows wave*32+c*8..+7, lane l -> row +(l>>3), sector l&7;
  // linear offset (l>>3)*64 + (l&7)*8 == l*8 ushorts.
  auto writeA = [&](int buf, const uint4 (&P)[4]) {
#pragma unroll
    for (int c = 0; c < 4; ++c)
      *(uint4*)(&Alds[buf][(wave * 32 + c * 8) * 64 + lane * 8]) = P[c];
  };
  // B frags for step t: slabs 2t, 2t+1 (each 8 KB, layout [q][co*8+e])
  auto loadB = [&](int t) {
#pragma unroll
    for (int kk = 0; kk < 2; ++kk) {
      const unsigned short* base =
          Wt + (size_t)(2 * t + kk) * 4096 + q * 1024 + m * 8;
#pragma unroll
      for (int j = 0; j < 4; ++j)
        b[kk][j] = *(const frag_ab*)(base + (wcol + 16 * j) * 8);
    }
  };
  auto do_mfma = [&](int abuf) {
#pragma unroll
    for (int kk = 0; kk < 2; ++kk) {
      frag_ab a[4];
#pragma unroll
      for (int i = 0; i < 4; ++i) {
        const int row = wrow + 16 * i + m;
        a[i] = *(const frag_ab*)(
            &Alds[abuf][row * 64 + ((kk * 4 + q) ^ (m & 7)) * 8]);
      }
#pragma unroll
      for (int i = 0; i < 4; ++i)
#pragma unroll
        for (int j = 0; j < 4; ++j)
          acc[i][j] = __builtin_amdgcn_mfma_f32_16x16x32_bf16(
              a[i], b[kk][j], acc[i][j], 0, 0, 0);
    }
  };

  const int T = koff * SUB;  // conv1: 27, conv2: 54

  // prologue: issue steps 0,1; write step 0 into buf0; idxc -> idx(ko(2))
  load_idx(0, idxc);
  issueA(P0, 0, idxc);
  if (SUB == 1) {
    if (1 < koff) load_idx(1, idxc);
    issueA(P1, 1, idxc);
  } else {
    issueA(P1, 1, idxc);  // step 1 = (ko 0, sub 1)
  }
  {
    const int ko2 = (SUB == 2) ? 1 : 2;  // ko of step 2
    if (ko2 < koff) load_idx(ko2, idxc);
  }
  writeA(0, P0);  // compiler waits P0's loads

  for (int t = 0; t < T; ++t) {
    __syncthreads();  // orders last iter's ds_writes & this iter's reads
    const int u1 = t + 1;
    if (u1 < T) {
      if (u1 & 1) writeA(1, P1); else writeA(0, P0);
    }
    const int u2 = t + 2;
    if (u2 < T) {
      if (u2 & 1) issueA(P1, u2, idxc); else issueA(P0, u2, idxc);
      if (SUB == 1 || (u2 & 1)) {  // ko changes at u2+1
        const int kon = (SUB == 2) ? ((u2 + 1) >> 1) : (u2 + 1);
        if (kon < koff) load_idx(kon, idxc);
      }
    }
    loadB(t);
    do_mfma(t & 1);
  }

  // fused BN stats
#pragma unroll
  for (int j = 0; j < 4; ++j) {
    float s = 0.f, qq = 0.f;
#pragma unroll
    for (int i = 0; i < 4; ++i)
#pragma unroll
      for (int r = 0; r < 4; ++r) {
        float v = acc[i][j][r];
        s += v; qq += v * v;
      }
    s += __shfl_xor(s, 16); s += __shfl_xor(s, 32);
    qq += __shfl_xor(qq, 16); qq += __shfl_xor(qq, 32);
    if (lane < 16) {
      const int col = wcol + 16 * j + lane;
      atomicAdd(&sums[col], s);
      atomicAdd(&sums[COUT + col], qq);
    }
  }

  // epilogue: C/D layout col=lane&15, row=(lane>>4)*4+reg
#pragma unroll
  for (int i = 0; i < 4; ++i) {
#pragma unroll
    for (int r = 0; r < 4; ++r) {
      const int grow = row0 + wrow + 16 * i + q * 4 + r;
      if (grow < n) {
#pragma unroll
        for (int j = 0; j < 4; ++j) {
          const int gcol = wcol + 16 * j + m;
          if (OF32)
            ((float*)Yv)[(size_t)grow * COUT + gcol] = acc[i][j][r];
          else
            ((unsigned short*)Yv)[(size_t)grow * COUT + gcol] = f2bf(acc[i][j][r]);
        }
      }
    }
  }
}

// ---------------------------------------------------------------------------
// Fused: fp32->bf16 convert of feats (writes featsb, channel-linear) + skip
// GEMM feats@Wd + fused skip BN stats. Internal LDS uses its own (old
// 4-sector) swizzle — self-consistent, independent of conv_kernel.
// ---------------------------------------------------------------------------
__global__ __launch_bounds__(256, 2) void convskip_kernel(
    const float* __restrict__ feats, const float* __restrict__ Wd,
    unsigned short* __restrict__ featsb, unsigned short* __restrict__ sX,
    float* __restrict__ sums, int n) {
  __shared__ unsigned short Alds[2][128 * 32];
  const int tid = threadIdx.x;
  const int lane = tid & 63;
  const int wave = tid >> 6;
  const int row0 = blockIdx.x * 128;
  const int wrow = (wave >> 1) * 64;
  const int wcol = (wave & 1) * 64;
  const int m = lane & 15;
  const int q = lane >> 4;

  // stage A (+ write featsb): 1024 units = (kc, row, s)
#pragma unroll
  for (int c = 0; c < 4; ++c) {
    int u = c * 256 + tid;
    int kc = u >> 9;
    int v = u & 511;
    int row = v >> 2;
    int s = v & 3;
    int g = s ^ ((row >> 1) & 3);
    int grow = row0 + row;
    uint4 out = make_uint4(0u, 0u, 0u, 0u);
    if (grow < n) {
      const float* p = feats + (size_t)grow * 64 + kc * 32 + g * 8;
      float4 lo = *(const float4*)p;
      float4 hi = *(const float4*)(p + 4);
      out.x = (unsigned)f2bf(lo.x) | ((unsigned)f2bf(lo.y) << 16);
      out.y = (unsigned)f2bf(lo.z) | ((unsigned)f2bf(lo.w) << 16);
      out.z = (unsigned)f2bf(hi.x) | ((unsigned)f2bf(hi.y) << 16);
      out.w = (unsigned)f2bf(hi.z) | ((unsigned)f2bf(hi.w) << 16);
      *(uint4*)(featsb + (size_t)grow * 64 + kc * 32 + g * 8) = out;
    }
    *(uint4*)(&Alds[kc][row * 32 + s * 8]) = out;
  }
  __syncthreads();

  frag_cd acc[4][4];
#pragma unroll
  for (int i = 0; i < 4; ++i)
#pragma unroll
    for (int j = 0; j < 4; ++j) acc[i][j] = (frag_cd){0.f, 0.f, 0.f, 0.f};

#pragma unroll
  for (int kc = 0; kc < 2; ++kc) {
    frag_ab b[4];
#pragma unroll
    for (int j = 0; j < 4; ++j) {
      const int co = wcol + 16 * j + m;
#pragma unroll
      for (int e = 0; e < 8; ++e)
        b[j][e] = (short)f2bf(Wd[(size_t)(kc * 32 + q * 8 + e) * 128 + co]);
    }
    frag_ab a[4];
#pragma unroll
    for (int i = 0; i < 4; ++i) {
      const int row = wrow + 16 * i + m;
      a[i] = *(const frag_ab*)(&Alds[kc][row * 32 + (q ^ ((row >> 1) & 3)) * 8]);
    }
#pragma unroll
    for (int i = 0; i < 4; ++i)
#pragma unroll
      for (int j = 0; j < 4; ++j)
        acc[i][j] = __builtin_amdgcn_mfma_f32_16x16x32_bf16(a[i], b[j],
                                                            acc[i][j], 0, 0, 0);
  }

  // fused BN stats (tail rows contribute exact zeros)
#pragma unroll
  for (int j = 0; j < 4; ++j) {
    float s = 0.f, qq = 0.f;
#pragma unroll
    for (int i = 0; i < 4; ++i)
#pragma unroll
      for (int r = 0; r < 4; ++r) {
        float v = acc[i][j][r];
        s += v; qq += v * v;
      }
    s += __shfl_xor(s, 16); s += __shfl_xor(s, 32);
    qq += __shfl_xor(qq, 16); qq += __shfl_xor(qq, 32);
    if (lane < 16) {
      const int col = wcol + 16 * j + lane;
      atomicAdd(&sums[col], s);
      atomicAdd(&sums[COUT + col], qq);
    }
  }

#pragma unroll
  for (int i = 0; i < 4; ++i) {
#pragma unroll
    for (int r = 0; r < 4; ++r) {
      const int grow = row0 + wrow + 16 * i + q * 4 + r;
      if (grow < n) {
#pragma unroll
        for (int j = 0; j < 4; ++j)
          sX[(size_t)grow * COUT + wcol + 16 * j + m] = f2bf(acc[i][j][r]);
      }
    }
  }
}

// ---------------------------------------------------------------------------
// prep: zero sums (768 floats) + zpage (64 floats) + Wt1/Wt2 slab transposes.
// slab layout: dst[((ko*nc+kc)*4+q)*1024 + co*8 + e] = bf16(src[ko][kc*32+q*8+e][co])
// ---------------------------------------------------------------------------
__global__ void prep_kernel(const float* __restrict__ W1,
                            const float* __restrict__ W2,
                            unsigned short* __restrict__ Wt1,
                            unsigned short* __restrict__ Wt2,
                            float* __restrict__ zbase,
                            float* __restrict__ zpage) {
  const int NZ = 768 + 64;
  const int NW1 = KOFF * CIN * 128;    // 221184
  const int NW2 = KOFF * COUT * 128;   // 442368
  int gid = blockIdx.x * 256 + threadIdx.x;
  if (gid < NZ) {
    if (gid < 768) zbase[gid] = 0.f; else zpage[gid - 768] = 0.f;
    return;
  }
  gid -= NZ;
  const float* src;
  unsigned short* dst;
  int ci;
  if (gid < NW1) { src = W1; dst = Wt1; ci = CIN; }
  else if (gid < NW1 + NW2) { gid -= NW1; src = W2; dst = Wt2; ci = COUT; }
  else return;
  int e = gid & 7;
  int co = (gid >> 3) & 127;
  int qq = (gid >> 10) & 3;
  int slab = gid >> 12;
  int nc = ci >> 5;
  int ko = slab / nc;
  int kc = slab - ko * nc;
  int cin = kc * 32 + qq * 8 + e;
  dst[gid] = f2bf(src[((size_t)ko * ci + cin) * 128 + co]);
}

// in-place bf16 x = relu(x*scale + shift); finalize fused (per-block LDS)
__global__ void norm_relu_kernel(unsigned short* __restrict__ x,
                                 const float* __restrict__ sums,
                                 const float* __restrict__ gamma,
                                 const float* __restrict__ beta,
                                 int n, int total8) {
  __shared__ float sc[COUT], sh[COUT];
  const int tid = threadIdx.x;
  if (tid < COUT) {
    float inv_n = 1.f / (float)n;
    float mean = sums[tid] * inv_n;
    float var = sums[COUT + tid] * inv_n - mean * mean;
    float s = gamma[tid] * rsqrtf(var + EPS);
    sc[tid] = s;
    sh[tid] = beta[tid] - mean * s;
  }
  __syncthreads();
  int gid = blockIdx.x * 256 + tid;
  if (gid >= total8) return;
  size_t i = (size_t)gid * 8;
  int c0 = (int)(i & 127);
  uint4 v = *(const uint4*)(x + i);
  unsigned int w[4] = {v.x, v.y, v.z, v.w};
  unsigned int wo[4];
#pragma unroll
  for (int e = 0; e < 4; ++e) {
    int c = c0 + 2 * e;
    float f0 = bf2f((unsigned short)(w[e] & 0xffffu));
    float f1 = bf2f((unsigned short)(w[e] >> 16));
    f0 = fmaxf(f0 * sc[c] + sh[c], 0.f);
    f1 = fmaxf(f1 * sc[c + 1] + sh[c + 1], 0.f);
    wo[e] = (unsigned int)f2bf(f0) | ((unsigned int)f2bf(f1) << 16);
  }
  *(uint4*)(x + i) = make_uint4(wo[0], wo[1], wo[2], wo[3]);
}

// out(fp32, in-place on h2) = relu(bn2(h2) + bnd(s)); finalize fused
__global__ void final_kernel(float* __restrict__ h2,
                             const unsigned short* __restrict__ s,
                             const float* __restrict__ sums2,
                             const float* __restrict__ sumsd,
                             const float* __restrict__ g2,
                             const float* __restrict__ b2,
                             const float* __restrict__ gd,
                             const float* __restrict__ bd,
                             int n, int total4) {
  __shared__ float sc2[COUT], sh2[COUT], scd[COUT], shd[COUT];
  const int tid = threadIdx.x;
  if (tid < COUT) {
    float inv_n = 1.f / (float)n;
    float mean = sums2[tid] * inv_n;
    float var = sums2[COUT + tid] * inv_n - mean * mean;
    float sa = g2[tid] * rsqrtf(var + EPS);
    sc2[tid] = sa;
    sh2[tid] = b2[tid] - mean * sa;
    mean = sumsd[tid] * inv_n;
    var = sumsd[COUT + tid] * inv_n - mean * mean;
    float sb = gd[tid] * rsqrtf(var + EPS);
    scd[tid] = sb;
    shd[tid] = bd[tid] - mean * sb;
  }
  __syncthreads();
  int gid = blockIdx.x * 256 + tid;
  if (gid >= total4) return;
  size_t i = (size_t)gid * 4;
  int c = (int)(i & 127);
  float4 a = *(const float4*)(h2 + i);
  uint2 sv = *(const uint2*)(s + i);
  float b0 = bf2f((unsigned short)(sv.x & 0xffffu));
  float b1 = bf2f((unsigned short)(sv.x >> 16));
  float b2f = bf2f((unsigned short)(sv.y & 0xffffu));
  float b3 = bf2f((unsigned short)(sv.y >> 16));
  float4 o;
  o.x = fmaxf(a.x * sc2[c] + sh2[c] + b0 * scd[c] + shd[c], 0.f);
  o.y = fmaxf(a.y * sc2[c + 1] + sh2[c + 1] + b1 * scd[c + 1] + shd[c + 1], 0.f);
  o.z = fmaxf(a.z * sc2[c + 2] + sh2[c + 2] + b2f * scd[c + 2] + shd[c + 2], 0.f);
  o.w = fmaxf(a.w * sc2[c + 3] + sh2[c + 3] + b3 * scd[c + 3] + shd[c + 3], 0.f);
  *(float4*)(h2 + i) = o;
}

extern "C" void kernel_launch(void* const* d_in, const int* in_sizes, int n_in,
                              void* d_out, int out_size, void* d_ws,
                              size_t ws_size, hipStream_t stream) {
  (void)n_in; (void)out_size; (void)ws_size;
  const float* feats = (const float*)d_in[0];
  const int* nbr1 = (const int*)d_in[1];
  const int* nbr2 = (const int*)d_in[2];
  const float* W1 = (const float*)d_in[3];
  const float* W2 = (const float*)d_in[4];
  const float* Wd = (const float*)d_in[5];
  const float* g1 = (const float*)d_in[6];
  const float* b1 = (const float*)d_in[7];
  const float* g2 = (const float*)d_in[8];
  const float* b2 = (const float*)d_in[9];
  const float* gd = (const float*)d_in[10];
  const float* bd = (const float*)d_in[11];

  const int n = in_sizes[0] / CIN;  // 200000

  // ws layout (known-good footprint):
  //   Wt1[442368] Wt2[884736] (hole) h1_bf16[51.2e6] sX_bf16[51.2e6]
  //   sums[3 KB in 8 KB slot] zpage[256]
  char* ws = (char*)d_ws;
  unsigned short* Wt1 = (unsigned short*)(ws);
  unsigned short* Wt2 = (unsigned short*)(ws + 442368);
  unsigned short* h1 = (unsigned short*)(ws + 1343488);
  unsigned short* sX = (unsigned short*)(ws + 52543488);
  float* sums1 = (float*)(ws + 103743488);
  float* sums2 = sums1 + 2 * COUT;
  float* sumsd = sums1 + 4 * COUT;
  unsigned short* zpage = (unsigned short*)(ws + 103743488 + 8192);

  float* h2 = (float*)d_out;  // conv2 output -> d_out (fp32)
  // bf16 feats stash: last 25.6 MB of d_out; conv2 clobbers it afterwards
  unsigned short* featsb = (unsigned short*)((char*)d_out + 76800000);

  const int prep_units = (768 + 64) + KOFF * CIN * 128 + KOFF * COUT * 128;
  prep_kernel<<<(prep_units + 255) / 256, 256, 0, stream>>>(
      W1, W2, Wt1, Wt2, sums1, (float*)zpage);

  const int mblocks = (n + 127) / 128;
  convskip_kernel<<<mblocks, 256, 0, stream>>>(feats, Wd, featsb, sX, sumsd, n);

  conv_kernel<CIN, true, false><<<mblocks, 256, 0, stream>>>(
      featsb, nbr1, Wt1, h1, zpage, sums1, n, KOFF);

  const int total8 = n * COUT / 8;
  norm_relu_kernel<<<(total8 + 255) / 256, 256, 0, stream>>>(h1, sums1, g1, b1, n, total8);

  conv_kernel<COUT, true, true><<<mblocks, 256, 0, stream>>>(
      h1, nbr2, Wt2, h2, zpage, sums2, n, KOFF);

  const int total4 = n * COUT / 4;
  final_kernel<<<(total4 + 255) / 256, 256, 0, stream>>>(
      h2, sX, sums2, sumsd, g2, b2, gd, bd, n, total4);
}

// Round 9
// 839.196 us; speedup vs baseline: 1.5543x; 1.5543x over previous
//
#include <hip/hip_runtime.h>
#include <stdint.h>

#define KOFF 27
#define CIN 64
#define COUT 128
#define EPS 1e-5f

using frag_ab = __attribute__((ext_vector_type(8))) short;
using frag_cd = __attribute__((ext_vector_type(4))) float;

__device__ __forceinline__ float bf2f(unsigned short u) {
  union { unsigned int i; float f; } x; x.i = ((unsigned int)u) << 16; return x.f;
}
__device__ __forceinline__ unsigned short f2bf(float f) {
  union { float f; unsigned int i; } x; x.f = f;
  unsigned int u = x.i;
  u += 0x7fffu + ((u >> 16) & 1u);   // round-to-nearest-even
  return (unsigned short)(u >> 16);
}

// ---------------------------------------------------------------------------
// Gather-GEMM (round 8 resubmit): Y[row] = sum_k X[nbr[k][row]] @ W[k].
// R5 skeleton (K=64 steps, __syncthreads, 2-buffer LDS ping-pong, 8-sector
// XOR swizzle, B JIT in registers) + reg-staged A (T14), SPILL-PROOF:
// pending sets are EIGHT NAMED uint4 scalars (pa0..3 even steps, pb0..3 odd
// steps), manual 2x loop unroll so every set/buf reference is a literal on a
// straight-line path (R7's arrays+runtime-parity defeated SROA -> scratch,
// WRITE_SIZE 103MB->1.4GB). Schedule per pair (t even):
//   iter t  : bar; write pb->buf1 (step t+1); issue pa<-step t+2; B(t); mfma(buf0)
//   iter t+1: bar; write pa->buf0 (step t+2); issue pb<-step t+3; B(t+1); mfma(buf1)
// Odd T (conv1=27): final compute-only tail iteration.
// Each load gets a full iteration of cover before its ds_write waits on it.
// Fused BN stats via zero-page trick + atomics.
// ---------------------------------------------------------------------------
template <int CI, bool GATHER, bool OF32>
__global__ __launch_bounds__(256, 3) void conv_kernel(
    const unsigned short* __restrict__ X, const int* __restrict__ nbr,
    const unsigned short* __restrict__ Wt, void* __restrict__ Yv,
    const unsigned short* __restrict__ zpage, float* __restrict__ sums,
    int n, int koff) {
  constexpr int SUB = CI / 64;  // 64-ch sub-chunks per offset (1 or 2)
  __shared__ unsigned short Alds[2][128 * 64];  // 2 x 16 KB ping-pong

  const int tid = threadIdx.x;
  const int lane = tid & 63;
  const int wave = tid >> 6;
  const int row0 = blockIdx.x * 128;
  const int wrow = (wave >> 1) * 64;
  const int wcol = (wave & 1) * 64;
  const int m = lane & 15;
  const int q = lane >> 4;
  const int g8 = ((lane & 7) ^ (lane >> 3)) * 8;  // swizzled sector (ushorts)

  frag_cd acc[4][4];
#pragma unroll
  for (int i = 0; i < 4; ++i)
#pragma unroll
    for (int j = 0; j < 4; ++j) acc[i][j] = (frag_cd){0.f, 0.f, 0.f, 0.f};

  frag_ab b[2][4];
  int idxc[4];
  uint4 pa0, pa1, pa2, pa3;  // pending A, even steps
  uint4 pb0, pb1, pb2, pb3;  // pending A, odd steps

  auto load_idx = [&](int ko) {
#pragma unroll
    for (int c = 0; c < 4; ++c) {
      const int grow = row0 + wave * 32 + c * 8 + (lane >> 3);
      int v = -1;
      if (grow < n) v = GATHER ? nbr[(size_t)ko * n + grow] : grow;
      idxc[c] = v;
    }
  };
  auto gaddr = [&](int c, int ch) -> const unsigned short* {
    return (idxc[c] >= 0) ? X + (size_t)idxc[c] * CI + ch : zpage;
  };
  // issue 4 x 16 B gathered loads for step u into named scalars
  auto issueA = [&](uint4& x0, uint4& x1, uint4& x2, uint4& x3, int u) {
    const int ch = (SUB == 2 ? (u & 1) * 64 : 0) + g8;
    x0 = *(const uint4*)gaddr(0, ch);
    x1 = *(const uint4*)gaddr(1, ch);
    x2 = *(const uint4*)gaddr(2, ch);
    x3 = *(const uint4*)gaddr(3, ch);
  };
  // ds_write set into buf; layout identical to R5's gld16 product:
  // chunk c covers rows wave*32+c*8..+7; lane l -> linear l*8 ushorts in chunk
  auto writeA = [&](int buf, const uint4& x0, const uint4& x1,
                    const uint4& x2, const uint4& x3) {
    unsigned short* base = &Alds[buf][wave * 2048 + lane * 8];
    *(uint4*)(base) = x0;
    *(uint4*)(base + 512) = x1;
    *(uint4*)(base + 1024) = x2;
    *(uint4*)(base + 1536) = x3;
  };
  // after issuing step u2, advance idxc to ko(u2+1) if ko changes
  auto adv_idx = [&](int u2) {
    if (SUB == 1 || (u2 & 1)) {
      const int kon = (SUB == 2) ? ((u2 + 1) >> 1) : (u2 + 1);
      if (kon < koff) load_idx(kon);
    }
  };
  // B frags for step t: slabs 2t, 2t+1 (each 8 KB, layout [q][co*8+e])
  auto loadB = [&](int t) {
#pragma unroll
    for (int kk = 0; kk < 2; ++kk) {
      const unsigned short* base =
          Wt + (size_t)(2 * t + kk) * 4096 + q * 1024 + m * 8;
#pragma unroll
      for (int j = 0; j < 4; ++j)
        b[kk][j] = *(const frag_ab*)(base + (wcol + 16 * j) * 8);
    }
  };
  auto do_mfma = [&](int abuf) {
#pragma unroll
    for (int kk = 0; kk < 2; ++kk) {
      frag_ab a[4];
#pragma unroll
      for (int i = 0; i < 4; ++i) {
        const int row = wrow + 16 * i + m;
        a[i] = *(const frag_ab*)(
            &Alds[abuf][row * 64 + ((kk * 4 + q) ^ (m & 7)) * 8]);
      }
#pragma unroll
      for (int i = 0; i < 4; ++i)
#pragma unroll
        for (int j = 0; j < 4; ++j)
          acc[i][j] = __builtin_amdgcn_mfma_f32_16x16x32_bf16(
              a[i], b[kk][j], acc[i][j], 0, 0, 0);
    }
  };

  const int T = koff * SUB;  // conv1: 27, conv2: 54

  // prologue: issue steps 0,1; idxc -> idx(ko of step 2); write step 0
  load_idx(0);
  issueA(pa0, pa1, pa2, pa3, 0);
  if (SUB == 1) {
    if (1 < koff) load_idx(1);
    issueA(pb0, pb1, pb2, pb3, 1);
    if (2 < koff) load_idx(2);
  } else {
    issueA(pb0, pb1, pb2, pb3, 1);  // step 1 = (ko 0, sub 1)
    if (1 < koff) load_idx(1);
  }
  writeA(0, pa0, pa1, pa2, pa3);  // compiler waits pa's loads here

  for (int t = 0; t + 1 < T; t += 2) {
    // ---- iter t (even): compute buf0
    __syncthreads();
    writeA(1, pb0, pb1, pb2, pb3);  // step t+1 (t+1 < T by loop bound)
    const int u2 = t + 2;
    if (u2 < T) {
      issueA(pa0, pa1, pa2, pa3, u2);
      adv_idx(u2);
    }
    loadB(t);
    do_mfma(0);

    // ---- iter t+1 (odd): compute buf1
    __syncthreads();
    const int u1b = t + 2;
    if (u1b < T) writeA(0, pa0, pa1, pa2, pa3);
    const int u2b = t + 3;
    if (u2b < T) {
      issueA(pb0, pb1, pb2, pb3, u2b);
      adv_idx(u2b);
    }
    loadB(t + 1);
    do_mfma(1);
  }
  if (T & 1) {  // tail step T-1 (even, already written to buf0)
    __syncthreads();
    loadB(T - 1);
    do_mfma(0);
  }

  // fused BN stats
#pragma unroll
  for (int j = 0; j < 4; ++j) {
    float s = 0.f, qq = 0.f;
#pragma unroll
    for (int i = 0; i < 4; ++i)
#pragma unroll
      for (int r = 0; r < 4; ++r) {
        float v = acc[i][j][r];
        s += v; qq += v * v;
      }
    s += __shfl_xor(s, 16); s += __shfl_xor(s, 32);
    qq += __shfl_xor(qq, 16); qq += __shfl_xor(qq, 32);
    if (lane < 16) {
      const int col = wcol + 16 * j + lane;
      atomicAdd(&sums[col], s);
      atomicAdd(&sums[COUT + col], qq);
    }
  }

  // epilogue: C/D layout col=lane&15, row=(lane>>4)*4+reg
#pragma unroll
  for (int i = 0; i < 4; ++i) {
#pragma unroll
    for (int r = 0; r < 4; ++r) {
      const int grow = row0 + wrow + 16 * i + q * 4 + r;
      if (grow < n) {
#pragma unroll
        for (int j = 0; j < 4; ++j) {
          const int gcol = wcol + 16 * j + m;
          if (OF32)
            ((float*)Yv)[(size_t)grow * COUT + gcol] = acc[i][j][r];
          else
            ((unsigned short*)Yv)[(size_t)grow * COUT + gcol] = f2bf(acc[i][j][r]);
        }
      }
    }
  }
}

// ---------------------------------------------------------------------------
// Fused: fp32->bf16 convert of feats (writes featsb, channel-linear) + skip
// GEMM feats@Wd + fused skip BN stats. Internal LDS uses its own (old
// 4-sector) swizzle — self-consistent, independent of conv_kernel.
// ---------------------------------------------------------------------------
__global__ __launch_bounds__(256, 2) void convskip_kernel(
    const float* __restrict__ feats, const float* __restrict__ Wd,
    unsigned short* __restrict__ featsb, unsigned short* __restrict__ sX,
    float* __restrict__ sums, int n) {
  __shared__ unsigned short Alds[2][128 * 32];
  const int tid = threadIdx.x;
  const int lane = tid & 63;
  const int wave = tid >> 6;
  const int row0 = blockIdx.x * 128;
  const int wrow = (wave >> 1) * 64;
  const int wcol = (wave & 1) * 64;
  const int m = lane & 15;
  const int q = lane >> 4;

  // stage A (+ write featsb): 1024 units = (kc, row, s)
#pragma unroll
  for (int c = 0; c < 4; ++c) {
    int u = c * 256 + tid;
    int kc = u >> 9;
    int v = u & 511;
    int row = v >> 2;
    int s = v & 3;
    int g = s ^ ((row >> 1) & 3);
    int grow = row0 + row;
    uint4 out = make_uint4(0u, 0u, 0u, 0u);
    if (grow < n) {
      const float* p = feats + (size_t)grow * 64 + kc * 32 + g * 8;
      float4 lo = *(const float4*)p;
      float4 hi = *(const float4*)(p + 4);
      out.x = (unsigned)f2bf(lo.x) | ((unsigned)f2bf(lo.y) << 16);
      out.y = (unsigned)f2bf(lo.z) | ((unsigned)f2bf(lo.w) << 16);
      out.z = (unsigned)f2bf(hi.x) | ((unsigned)f2bf(hi.y) << 16);
      out.w = (unsigned)f2bf(hi.z) | ((unsigned)f2bf(hi.w) << 16);
      *(uint4*)(featsb + (size_t)grow * 64 + kc * 32 + g * 8) = out;
    }
    *(uint4*)(&Alds[kc][row * 32 + s * 8]) = out;
  }
  __syncthreads();

  frag_cd acc[4][4];
#pragma unroll
  for (int i = 0; i < 4; ++i)
#pragma unroll
    for (int j = 0; j < 4; ++j) acc[i][j] = (frag_cd){0.f, 0.f, 0.f, 0.f};

#pragma unroll
  for (int kc = 0; kc < 2; ++kc) {
    frag_ab b[4];
#pragma unroll
    for (int j = 0; j < 4; ++j) {
      const int co = wcol + 16 * j + m;
#pragma unroll
      for (int e = 0; e < 8; ++e)
        b[j][e] = (short)f2bf(Wd[(size_t)(kc * 32 + q * 8 + e) * 128 + co]);
    }
    frag_ab a[4];
#pragma unroll
    for (int i = 0; i < 4; ++i) {
      const int row = wrow + 16 * i + m;
      a[i] = *(const frag_ab*)(&Alds[kc][row * 32 + (q ^ ((row >> 1) & 3)) * 8]);
    }
#pragma unroll
    for (int i = 0; i < 4; ++i)
#pragma unroll
      for (int j = 0; j < 4; ++j)
        acc[i][j] = __builtin_amdgcn_mfma_f32_16x16x32_bf16(a[i], b[j],
                                                            acc[i][j], 0, 0, 0);
  }

  // fused BN stats (tail rows contribute exact zeros)
#pragma unroll
  for (int j = 0; j < 4; ++j) {
    float s = 0.f, qq = 0.f;
#pragma unroll
    for (int i = 0; i < 4; ++i)
#pragma unroll
      for (int r = 0; r < 4; ++r) {
        float v = acc[i][j][r];
        s += v; qq += v * v;
      }
    s += __shfl_xor(s, 16); s += __shfl_xor(s, 32);
    qq += __shfl_xor(qq, 16); qq += __shfl_xor(qq, 32);
    if (lane < 16) {
      const int col = wcol + 16 * j + lane;
      atomicAdd(&sums[col], s);
      atomicAdd(&sums[COUT + col], qq);
    }
  }

#pragma unroll
  for (int i = 0; i < 4; ++i) {
#pragma unroll
    for (int r = 0; r < 4; ++r) {
      const int grow = row0 + wrow + 16 * i + q * 4 + r;
      if (grow < n) {
#pragma unroll
        for (int j = 0; j < 4; ++j)
          sX[(size_t)grow * COUT + wcol + 16 * j + m] = f2bf(acc[i][j][r]);
      }
    }
  }
}

// ---------------------------------------------------------------------------
// prep: zero sums (768 floats) + zpage (64 floats) + Wt1/Wt2 slab transposes.
// slab layout: dst[((ko*nc+kc)*4+q)*1024 + co*8 + e] = bf16(src[ko][kc*32+q*8+e][co])
// ---------------------------------------------------------------------------
__global__ void prep_kernel(const float* __restrict__ W1,
                            const float* __restrict__ W2,
                            unsigned short* __restrict__ Wt1,
                            unsigned short* __restrict__ Wt2,
                            float* __restrict__ zbase,
                            float* __restrict__ zpage) {
  const int NZ = 768 + 64;
  const int NW1 = KOFF * CIN * 128;    // 221184
  const int NW2 = KOFF * COUT * 128;   // 442368
  int gid = blockIdx.x * 256 + threadIdx.x;
  if (gid < NZ) {
    if (gid < 768) zbase[gid] = 0.f; else zpage[gid - 768] = 0.f;
    return;
  }
  gid -= NZ;
  const float* src;
  unsigned short* dst;
  int ci;
  if (gid < NW1) { src = W1; dst = Wt1; ci = CIN; }
  else if (gid < NW1 + NW2) { gid -= NW1; src = W2; dst = Wt2; ci = COUT; }
  else return;
  int e = gid & 7;
  int co = (gid >> 3) & 127;
  int qq = (gid >> 10) & 3;
  int slab = gid >> 12;
  int nc = ci >> 5;
  int ko = slab / nc;
  int kc = slab - ko * nc;
  int cin = kc * 32 + qq * 8 + e;
  dst[gid] = f2bf(src[((size_t)ko * ci + cin) * 128 + co]);
}

// in-place bf16 x = relu(x*scale + shift); finalize fused (per-block LDS)
__global__ void norm_relu_kernel(unsigned short* __restrict__ x,
                                 const float* __restrict__ sums,
                                 const float* __restrict__ gamma,
                                 const float* __restrict__ beta,
                                 int n, int total8) {
  __shared__ float sc[COUT], sh[COUT];
  const int tid = threadIdx.x;
  if (tid < COUT) {
    float inv_n = 1.f / (float)n;
    float mean = sums[tid] * inv_n;
    float var = sums[COUT + tid] * inv_n - mean * mean;
    float s = gamma[tid] * rsqrtf(var + EPS);
    sc[tid] = s;
    sh[tid] = beta[tid] - mean * s;
  }
  __syncthreads();
  int gid = blockIdx.x * 256 + tid;
  if (gid >= total8) return;
  size_t i = (size_t)gid * 8;
  int c0 = (int)(i & 127);
  uint4 v = *(const uint4*)(x + i);
  unsigned int w[4] = {v.x, v.y, v.z, v.w};
  unsigned int wo[4];
#pragma unroll
  for (int e = 0; e < 4; ++e) {
    int c = c0 + 2 * e;
    float f0 = bf2f((unsigned short)(w[e] & 0xffffu));
    float f1 = bf2f((unsigned short)(w[e] >> 16));
    f0 = fmaxf(f0 * sc[c] + sh[c], 0.f);
    f1 = fmaxf(f1 * sc[c + 1] + sh[c + 1], 0.f);
    wo[e] = (unsigned int)f2bf(f0) | ((unsigned int)f2bf(f1) << 16);
  }
  *(uint4*)(x + i) = make_uint4(wo[0], wo[1], wo[2], wo[3]);
}

// out(fp32, in-place on h2) = relu(bn2(h2) + bnd(s)); finalize fused
__global__ void final_kernel(float* __restrict__ h2,
                             const unsigned short* __restrict__ s,
                             const float* __restrict__ sums2,
                             const float* __restrict__ sumsd,
                             const float* __restrict__ g2,
                             const float* __restrict__ b2,
                             const float* __restrict__ gd,
                             const float* __restrict__ bd,
                             int n, int total4) {
  __shared__ float sc2[COUT], sh2[COUT], scd[COUT], shd[COUT];
  const int tid = threadIdx.x;
  if (tid < COUT) {
    float inv_n = 1.f / (float)n;
    float mean = sums2[tid] * inv_n;
    float var = sums2[COUT + tid] * inv_n - mean * mean;
    float sa = g2[tid] * rsqrtf(var + EPS);
    sc2[tid] = sa;
    sh2[tid] = b2[tid] - mean * sa;
    mean = sumsd[tid] * inv_n;
    var = sumsd[COUT + tid] * inv_n - mean * mean;
    float sb = gd[tid] * rsqrtf(var + EPS);
    scd[tid] = sb;
    shd[tid] = bd[tid] - mean * sb;
  }
  __syncthreads();
  int gid = blockIdx.x * 256 + tid;
  if (gid >= total4) return;
  size_t i = (size_t)gid * 4;
  int c = (int)(i & 127);
  float4 a = *(const float4*)(h2 + i);
  uint2 sv = *(const uint2*)(s + i);
  float b0 = bf2f((unsigned short)(sv.x & 0xffffu));
  float b1 = bf2f((unsigned short)(sv.x >> 16));
  float b2f = bf2f((unsigned short)(sv.y & 0xffffu));
  float b3 = bf2f((unsigned short)(sv.y >> 16));
  float4 o;
  o.x = fmaxf(a.x * sc2[c] + sh2[c] + b0 * scd[c] + shd[c], 0.f);
  o.y = fmaxf(a.y * sc2[c + 1] + sh2[c + 1] + b1 * scd[c + 1] + shd[c + 1], 0.f);
  o.z = fmaxf(a.z * sc2[c + 2] + sh2[c + 2] + b2f * scd[c + 2] + shd[c + 2], 0.f);
  o.w = fmaxf(a.w * sc2[c + 3] + sh2[c + 3] + b3 * scd[c + 3] + shd[c + 3], 0.f);
  *(float4*)(h2 + i) = o;
}

extern "C" void kernel_launch(void* const* d_in, const int* in_sizes, int n_in,
                              void* d_out, int out_size, void* d_ws,
                              size_t ws_size, hipStream_t stream) {
  (void)n_in; (void)out_size; (void)ws_size;
  const float* feats = (const float*)d_in[0];
  const int* nbr1 = (const int*)d_in[1];
  const int* nbr2 = (const int*)d_in[2];
  const float* W1 = (const float*)d_in[3];
  const float* W2 = (const float*)d_in[4];
  const float* Wd = (const float*)d_in[5];
  const float* g1 = (const float*)d_in[6];
  const float* b1 = (const float*)d_in[7];
  const float* g2 = (const float*)d_in[8];
  const float* b2 = (const float*)d_in[9];
  const float* gd = (const float*)d_in[10];
  const float* bd = (const float*)d_in[11];

  const int n = in_sizes[0] / CIN;  // 200000

  // ws layout (known-good footprint):
  //   Wt1[442368] Wt2[884736] (hole) h1_bf16[51.2e6] sX_bf16[51.2e6]
  //   sums[3 KB in 8 KB slot] zpage[256]
  char* ws = (char*)d_ws;
  unsigned short* Wt1 = (unsigned short*)(ws);
  unsigned short* Wt2 = (unsigned short*)(ws + 442368);
  unsigned short* h1 = (unsigned short*)(ws + 1343488);
  unsigned short* sX = (unsigned short*)(ws + 52543488);
  float* sums1 = (float*)(ws + 103743488);
  float* sums2 = sums1 + 2 * COUT;
  float* sumsd = sums1 + 4 * COUT;
  unsigned short* zpage = (unsigned short*)(ws + 103743488 + 8192);

  float* h2 = (float*)d_out;  // conv2 output -> d_out (fp32)
  // bf16 feats stash: last 25.6 MB of d_out; conv2 clobbers it afterwards
  unsigned short* featsb = (unsigned short*)((char*)d_out + 76800000);

  const int prep_units = (768 + 64) + KOFF * CIN * 128 + KOFF * COUT * 128;
  prep_kernel<<<(prep_units + 255) / 256, 256, 0, stream>>>(
      W1, W2, Wt1, Wt2, sums1, (float*)zpage);

  const int mblocks = (n + 127) / 128;
  convskip_kernel<<<mblocks, 256, 0, stream>>>(feats, Wd, featsb, sX, sumsd, n);

  conv_kernel<CIN, true, false><<<mblocks, 256, 0, stream>>>(
      featsb, nbr1, Wt1, h1, zpage, sums1, n, KOFF);

  const int total8 = n * COUT / 8;
  norm_relu_kernel<<<(total8 + 255) / 256, 256, 0, stream>>>(h1, sums1, g1, b1, n, total8);

  conv_kernel<COUT, true, true><<<mblocks, 256, 0, stream>>>(
      h1, nbr2, Wt2, h2, zpage, sums2, n, KOFF);

  const int total4 = n * COUT / 4;
  final_kernel<<<(total4 + 255) / 256, 256, 0, stream>>>(
      h2, sX, sums2, sumsd, g2, b2, gd, bd, n, total4);
}